// Round 1
// baseline (424.043 us; speedup 1.0000x reference)
//
#include <hip/hip_runtime.h>

// AdaptiveEmbedding: VOCAB=50000, cutoffs [20000,40000], EMBED_DIM=1024, factor 4, pad=1
// cluster 0: ids [0,20000)    -> emb0 [20000,1024], direct gather
// cluster 1: ids [20000,40000)-> emb1 [20000,256]  @ proj1[1024,256]^T
// cluster 2: ids [40000,50000)-> emb2 [10000,64]   @ proj2[1024,64]^T

constexpr int NTOK = 8 * 4096;
constexpr int C1 = 20000;
constexpr int C2 = 40000;
constexpr int DIM = 1024;
constexpr int PAD = 1;

__global__ void classify_k(const int* __restrict__ ids, int* __restrict__ list1,
                           int* __restrict__ list2, int* __restrict__ counters) {
    int i = blockIdx.x * blockDim.x + threadIdx.x;
    if (i >= NTOK) return;
    int id = ids[i];
    if (id >= C1) {
        if (id < C2) list1[atomicAdd(&counters[0], 1)] = i;
        else         list2[atomicAdd(&counters[1], 1)] = i;
    }
}

// cluster 0: one block per token, 256 threads x float4 = 1024 floats
__global__ void copy0_k(const int* __restrict__ ids, const float* __restrict__ emb0,
                        float* __restrict__ out) {
    int tok = blockIdx.x;
    int id = ids[tok];
    if (id >= C1) return;
    float4 v = make_float4(0.f, 0.f, 0.f, 0.f);
    if (id != PAD) v = ((const float4*)emb0)[(size_t)id * (DIM / 4) + threadIdx.x];
    ((float4*)out)[(size_t)tok * (DIM / 4) + threadIdx.x] = v;
}

// clusters 1/2: batch 16 tokens per block; emb rows in LDS (broadcast reads),
// each thread owns 4 output dims (2 at a time), 16-token reuse per proj element.
template<int D>
__global__ void proj_k(const int* __restrict__ ids, const float* __restrict__ emb,
                       const float* __restrict__ proj, const int* __restrict__ list,
                       const int* __restrict__ count_ptr, int base,
                       float* __restrict__ out) {
    constexpr int D4 = D / 4;
    __shared__ float4 s_emb[16][D4];
    __shared__ int s_tok[16];
    __shared__ int s_loc[16];

    int count = *count_ptr;
    int t0 = blockIdx.x * 16;
    if (t0 >= count) return;
    int nt = min(16, count - t0);
    int tid = threadIdx.x;

    if (tid < 16) {
        int tokidx = -1, loc = -1;
        if (tid < nt) {
            tokidx = list[t0 + tid];
            int id = ids[tokidx];
            loc = id - base;          // in-cluster guaranteed, in range
            if (loc == PAD) loc = -1; // padding row is zero
        }
        s_tok[tid] = tokidx;
        s_loc[tid] = loc;
    }
    __syncthreads();

    // stage 16 emb rows into LDS (coalesced: 64/16 consecutive lanes per row)
    constexpr int TOTAL = 16 * D4;
    for (int f = tid; f < TOTAL; f += 256) {
        int t = f / D4;
        int d4 = f % D4;
        int loc = s_loc[t];
        float4 v = make_float4(0.f, 0.f, 0.f, 0.f);
        if (loc >= 0) v = ((const float4*)emb)[(size_t)loc * D4 + d4];
        s_emb[t][d4] = v;
    }
    __syncthreads();

    #pragma unroll
    for (int kk = 0; kk < 2; ++kk) {
        int e0 = tid + 512 * kk;
        int e1 = e0 + 256;
        const float4* pr0 = (const float4*)(proj + (size_t)e0 * D);
        const float4* pr1 = (const float4*)(proj + (size_t)e1 * D);
        float acc0[16], acc1[16];
        #pragma unroll
        for (int t = 0; t < 16; ++t) { acc0[t] = 0.f; acc1[t] = 0.f; }
        for (int d4 = 0; d4 < D4; ++d4) {
            float4 p0 = pr0[d4];
            float4 p1 = pr1[d4];
            #pragma unroll
            for (int t = 0; t < 16; ++t) {
                float4 ev = s_emb[t][d4];  // wave-uniform -> LDS broadcast
                acc0[t] += p0.x * ev.x + p0.y * ev.y + p0.z * ev.z + p0.w * ev.w;
                acc1[t] += p1.x * ev.x + p1.y * ev.y + p1.z * ev.z + p1.w * ev.w;
            }
        }
        for (int t = 0; t < nt; ++t) {
            size_t row = (size_t)s_tok[t] * DIM;
            out[row + e0] = acc0[t];
            out[row + e1] = acc1[t];
        }
    }
}

extern "C" void kernel_launch(void* const* d_in, const int* in_sizes, int n_in,
                              void* d_out, int out_size, void* d_ws, size_t ws_size,
                              hipStream_t stream) {
    const int*   ids   = (const int*)d_in[0];
    const float* emb0  = (const float*)d_in[1];
    const float* emb1  = (const float*)d_in[2];
    const float* emb2  = (const float*)d_in[3];
    const float* proj1 = (const float*)d_in[4];
    const float* proj2 = (const float*)d_in[5];
    float* out = (float*)d_out;

    int* counters = (int*)d_ws;                    // [0]=count1, [1]=count2
    int* list1 = (int*)((char*)d_ws + 64);
    int* list2 = list1 + NTOK;

    hipMemsetAsync(d_ws, 0, 64, stream);           // reset counters every call
    classify_k<<<NTOK / 256, 256, 0, stream>>>(ids, list1, list2, counters);
    copy0_k<<<NTOK, 256, 0, stream>>>(ids, emb0, out);
    proj_k<256><<<NTOK / 16, 256, 0, stream>>>(ids, emb1, proj1, list1, &counters[0], C1, out);
    proj_k<64><<<NTOK / 16, 256, 0, stream>>>(ids, emb2, proj2, list2, &counters[1], C2, out);
}

// Round 2
// 243.727 us; speedup vs baseline: 1.7398x; 1.7398x over previous
//
#include <hip/hip_runtime.h>

// AdaptiveEmbedding: VOCAB=50000, cutoffs [20000,40000], EMBED_DIM=1024, pad=1
// cluster 0: ids [0,20000)     -> emb0 [20000,1024], direct f32 gather
// cluster 1: ids [20000,40000) -> emb1 [20000,256]  @ proj1[1024,256]^T  (bf16 MFMA)
// cluster 2: ids [40000,50000) -> emb2 [10000,64]   @ proj2[1024,64]^T   (bf16 MFMA)

constexpr int NTOK = 8 * 4096;
constexpr int C1 = 20000;
constexpr int C2 = 40000;
constexpr int DIM = 1024;
constexpr int PAD = 1;
constexpr int K1 = 256, K2 = 64;
constexpr int NP1 = DIM * K1;   // proj1 element count
constexpr int NP2 = DIM * K2;

typedef unsigned short u16;
typedef unsigned int u32;
typedef __attribute__((ext_vector_type(8))) short bf16x8;
typedef __attribute__((ext_vector_type(4))) float f32x4;

__device__ __forceinline__ u16 f2bf(float f) {   // RNE f32 -> bf16
    u32 u = __builtin_bit_cast(u32, f);
    return (u16)((u + 0x7FFFu + ((u >> 16) & 1u)) >> 16);
}

__global__ void classify_k(const int* __restrict__ ids, u16* __restrict__ list1,
                           u16* __restrict__ list2, int* __restrict__ counters) {
    int i = blockIdx.x * blockDim.x + threadIdx.x;
    int id = ids[i];
    if (id >= C1) {
        if (id < C2) list1[atomicAdd(&counters[0], 1)] = (u16)i;
        else         list2[atomicAdd(&counters[1], 1)] = (u16)i;
    }
}

// convert proj1 ++ proj2 (f32) -> contiguous bf16 buffer in ws
__global__ void cvtproj_k(const float* __restrict__ proj1, const float* __restrict__ proj2,
                          u16* __restrict__ dst) {
    int i8 = (blockIdx.x * 256 + threadIdx.x) * 8;
    const float* src = proj1;
    int off = i8;
    if (i8 >= NP1) { src = proj2; off = i8 - NP1; }
    float4 a = ((const float4*)src)[off / 4];
    float4 b = ((const float4*)src)[off / 4 + 1];
    u16 t[8] = {f2bf(a.x), f2bf(a.y), f2bf(a.z), f2bf(a.w),
                f2bf(b.x), f2bf(b.y), f2bf(b.z), f2bf(b.w)};
    *(int4*)(dst + i8) = *(const int4*)t;
}

// cluster 0: one block per token, 256 threads x float4 = 1024 floats
__global__ void copy0_k(const int* __restrict__ ids, const float* __restrict__ emb0,
                        float* __restrict__ out) {
    int tok = blockIdx.x;
    int id = ids[tok];
    if (id >= C1) return;
    float4 v = make_float4(0.f, 0.f, 0.f, 0.f);
    if (id != PAD) v = ((const float4*)emb0)[(size_t)id * (DIM / 4) + threadIdx.x];
    ((float4*)out)[(size_t)tok * (DIM / 4) + threadIdx.x] = v;
}

// MFMA GEMM: 32 tokens x 1024 outputs per block. 4 waves: wave w owns n in
// [w*256, w*256+256) = 16 n-tiles, 2 m-tiles. A (gathered emb rows, bf16) in
// LDS with +8 u16 row pad (2-way bank alias = free). B fragments from global
// (bf16 pre-converted if PREBF, else f32 + on-the-fly cvt).
template<int K, bool PREBF>
__global__ __launch_bounds__(256) void gemm_k(const int* __restrict__ ids,
        const float* __restrict__ emb, const u16* __restrict__ projbf,
        const float* __restrict__ projf, const u16* __restrict__ list,
        const int* __restrict__ count_ptr, int base, float* __restrict__ out) {
    constexpr int K8 = K / 8;
    constexpr int LROW = K + 8;                 // u16 units; row stride 16B-aligned
    __shared__ __align__(16) u16 A[32][LROW];
    __shared__ u16 s_tok[32];
    __shared__ int s_loc[32];

    int count = *count_ptr;
    int t0 = blockIdx.x * 32;
    if (t0 >= count) return;
    int nt = min(32, count - t0);
    int tid = threadIdx.x;

    if (tid < 32) {
        int tokidx = 0, loc = -1;
        if (tid < nt) {
            tokidx = list[t0 + tid];
            loc = ids[tokidx] - base;           // in range by construction
            if (loc == PAD) loc = -1;           // padding row -> zeros
        }
        s_tok[tid] = (u16)tokidx;
        s_loc[tid] = loc;
    }
    __syncthreads();

    // stage A: 32 rows x K f32 -> bf16, 8 elems (16B) per chunk
    for (int c = tid; c < 32 * K8; c += 256) {
        int m = c / K8, k8 = c % K8;
        int loc = s_loc[m];
        float4 v0 = make_float4(0.f,0.f,0.f,0.f), v1 = v0;
        if (loc >= 0) {
            const float4* p = (const float4*)(emb + (size_t)loc * K) + k8 * 2;
            v0 = p[0]; v1 = p[1];
        }
        u16 t[8] = {f2bf(v0.x), f2bf(v0.y), f2bf(v0.z), f2bf(v0.w),
                    f2bf(v1.x), f2bf(v1.y), f2bf(v1.z), f2bf(v1.w)};
        *(int4*)&A[m][k8 * 8] = *(const int4*)t;
    }
    __syncthreads();

    int wave = tid >> 6;
    int lane = tid & 63;
    int lr = lane & 15;            // row-within-16 (A: m, B: n)
    int lk = (lane >> 4) * 8;      // k offset within 32-K step
    int nb = wave * 256;

    f32x4 acc[2][16] = {};
    for (int ks = 0; ks < K; ks += 32) {
        bf16x8 a0 = *(const bf16x8*)&A[lr][ks + lk];
        bf16x8 a1 = *(const bf16x8*)&A[16 + lr][ks + lk];
        #pragma unroll
        for (int ntile = 0; ntile < 16; ++ntile) {
            int n = nb + ntile * 16 + lr;
            bf16x8 b;
            if constexpr (PREBF) {
                b = *(const bf16x8*)&projbf[(size_t)n * K + ks + lk];
            } else {
                const float4* bp = (const float4*)(projf + (size_t)n * K + ks + lk);
                float4 b0 = bp[0], b1 = bp[1];
                u16 t[8] = {f2bf(b0.x), f2bf(b0.y), f2bf(b0.z), f2bf(b0.w),
                            f2bf(b1.x), f2bf(b1.y), f2bf(b1.z), f2bf(b1.w)};
                b = *(const bf16x8*)t;
            }
            acc[0][ntile] = __builtin_amdgcn_mfma_f32_16x16x32_bf16(a0, b, acc[0][ntile], 0, 0, 0);
            acc[1][ntile] = __builtin_amdgcn_mfma_f32_16x16x32_bf16(a1, b, acc[1][ntile], 0, 0, 0);
        }
    }

    // C/D layout (m89-verified): col(n) = lane&15, row(m) = (lane>>4)*4 + reg
    int rbase = (lane >> 4) * 4;
    #pragma unroll
    for (int mt = 0; mt < 2; ++mt) {
        #pragma unroll
        for (int r = 0; r < 4; ++r) {
            int trow = mt * 16 + rbase + r;
            if (trow < nt) {
                float* orow = out + (size_t)s_tok[trow] * DIM + nb + lr;
                #pragma unroll
                for (int ntile = 0; ntile < 16; ++ntile)
                    orow[ntile * 16] = acc[mt][ntile][r];
            }
        }
    }
}

extern "C" void kernel_launch(void* const* d_in, const int* in_sizes, int n_in,
                              void* d_out, int out_size, void* d_ws, size_t ws_size,
                              hipStream_t stream) {
    const int*   ids   = (const int*)d_in[0];
    const float* emb0  = (const float*)d_in[1];
    const float* emb1  = (const float*)d_in[2];
    const float* emb2  = (const float*)d_in[3];
    const float* proj1 = (const float*)d_in[4];
    const float* proj2 = (const float*)d_in[5];
    float* out = (float*)d_out;

    int* counters = (int*)d_ws;                         // [0]=count1, [1]=count2
    u16* list1 = (u16*)((char*)d_ws + 64);
    u16* list2 = list1 + NTOK;
    u16* projbf = (u16*)((char*)d_ws + 64 + 2 * NTOK * sizeof(u16));  // 16B aligned
    const size_t NEED_FULL = 64 + 2 * NTOK * sizeof(u16) + (size_t)(NP1 + NP2) * sizeof(u16);
    bool prebf = ws_size >= NEED_FULL;

    hipMemsetAsync(d_ws, 0, 64, stream);                // reset counters every call
    classify_k<<<NTOK / 256, 256, 0, stream>>>(ids, list1, list2, counters);
    if (prebf)
        cvtproj_k<<<(NP1 + NP2) / (256 * 8), 256, 0, stream>>>(proj1, proj2, projbf);
    copy0_k<<<NTOK, 256, 0, stream>>>(ids, emb0, out);
    if (prebf) {
        gemm_k<K1, true><<<NTOK / 32, 256, 0, stream>>>(ids, emb1, projbf, proj1,
                list1, &counters[0], C1, out);
        gemm_k<K2, true><<<NTOK / 32, 256, 0, stream>>>(ids, emb2, projbf + NP1, proj2,
                list2, &counters[1], C2, out);
    } else {
        gemm_k<K1, false><<<NTOK / 32, 256, 0, stream>>>(ids, emb1, projbf, proj1,
                list1, &counters[0], C1, out);
        gemm_k<K2, false><<<NTOK / 32, 256, 0, stream>>>(ids, emb2, projbf, proj2,
                list2, &counters[1], C2, out);
    }
}

// Round 3
// 84.696 us; speedup vs baseline: 5.0066x; 2.8776x over previous
//
#include <hip/hip_runtime.h>

// AdaptiveEmbedding: VOCAB=50000, cutoffs [20000,40000], EMBED_DIM=1024, pad=1
// cluster 0: ids [0,20000)     -> emb0 [20000,1024], direct f32 gather
// cluster 1: ids [20000,40000) -> emb1 [20000,256]  @ proj1[1024,256]^T  (bf16 MFMA)
// cluster 2: ids [40000,50000) -> emb2 [10000,64]   @ proj2[1024,64]^T   (bf16 MFMA)

constexpr int NTOK = 8 * 4096;
constexpr int C1 = 20000;
constexpr int C2 = 40000;
constexpr int DIM = 1024;
constexpr int PAD = 1;
constexpr int K1 = 256, K2 = 64;
constexpr int NP1 = DIM * K1;
constexpr int NP2 = DIM * K2;

typedef unsigned short u16;
typedef unsigned int u32;
typedef unsigned long long u64;
typedef __attribute__((ext_vector_type(8))) short bf16x8;
typedef __attribute__((ext_vector_type(4))) float f32x4;

__device__ __forceinline__ u16 f2bf(float f) {   // RNE f32 -> bf16
    u32 u = __builtin_bit_cast(u32, f);
    return (u16)((u + 0x7FFFu + ((u >> 16) & 1u)) >> 16);
}

// Compaction with ONE global atomic per list per block (Guideline 12):
// ballot -> per-wave count -> LDS scan -> block atomic -> scattered writes.
// counters[0] and counters[16] live on separate 64B lines.
__global__ __launch_bounds__(512) void classify_k(const int* __restrict__ ids,
        u16* __restrict__ list1, u16* __restrict__ list2, int* __restrict__ counters) {
    __shared__ int woff1[8], woff2[8];
    __shared__ int base1, base2;
    int tid = threadIdx.x;
    int i = blockIdx.x * 512 + tid;
    int id = ids[i];
    bool in1 = (id >= C1) & (id < C2);
    bool in2 = (id >= C2);
    u64 b1 = __ballot(in1);
    u64 b2 = __ballot(in2);
    int wave = tid >> 6, lane = tid & 63;
    if (lane == 0) { woff1[wave] = __popcll(b1); woff2[wave] = __popcll(b2); }
    __syncthreads();
    if (tid == 0) {
        int t1 = 0, t2 = 0;
        #pragma unroll
        for (int w = 0; w < 8; ++w) {
            int c1 = woff1[w]; woff1[w] = t1; t1 += c1;
            int c2 = woff2[w]; woff2[w] = t2; t2 += c2;
        }
        base1 = atomicAdd(&counters[0], t1);
        base2 = atomicAdd(&counters[16], t2);
    }
    __syncthreads();
    u64 lt = (lane == 63) ? ~0ull >> 1 : (1ull << lane) - 1;
    if (in1) list1[base1 + woff1[wave] + __popcll(b1 & lt)] = (u16)i;
    if (in2) list2[base2 + woff2[wave] + __popcll(b2 & lt)] = (u16)i;
}

// proj (f32 [DIM][K]) -> bf16 in MFMA fragment order: [ntile][kstep][lane][8elem]
// so each B fragment load in gemm_k is a contiguous, coalesced 1KB wave read.
template<int K>
__global__ void cvtprojL_k(const float* __restrict__ src, u16* __restrict__ dst) {
    constexpr int KS = K / 32;
    int idx = blockIdx.x * 256 + threadIdx.x;        // fragment chunk id
    int lane = idx & 63;
    int rest = idx >> 6;
    int kstep = rest % KS;
    int ntile = rest / KS;
    int n = ntile * 16 + (lane & 15);
    int k = kstep * 32 + (lane >> 4) * 8;
    const float4* p = (const float4*)(src + (size_t)n * K + k);
    float4 a = p[0], b = p[1];
    u16 t[8] = {f2bf(a.x), f2bf(a.y), f2bf(a.z), f2bf(a.w),
                f2bf(b.x), f2bf(b.y), f2bf(b.z), f2bf(b.w)};
    *(int4*)(dst + (size_t)idx * 8) = *(const int4*)t;
}

// cluster 0: one block per token, 256 threads x float4 = 1024 floats
__global__ void copy0_k(const int* __restrict__ ids, const float* __restrict__ emb0,
                        float* __restrict__ out) {
    int tok = blockIdx.x;
    int id = ids[tok];
    if (id >= C1) return;
    float4 v = make_float4(0.f, 0.f, 0.f, 0.f);
    if (id != PAD) v = ((const float4*)emb0)[(size_t)id * (DIM / 4) + threadIdx.x];
    ((float4*)out)[(size_t)tok * (DIM / 4) + threadIdx.x] = v;
}

// MFMA GEMM: 32 tokens x 1024 outputs per block. 4 waves, wave w owns n in
// [w*256, w*256+256): 16 n-tiles x 2 m-tiles. A staged in LDS (bf16, +8 pad:
// row stride 132 words == 4 mod 32 -> 2-way bank alias = free). B read from
// fragment-ordered bf16 (contiguous 1KB per wave per fragment).
template<int K>
__global__ __launch_bounds__(256) void gemm_k(const int* __restrict__ ids,
        const float* __restrict__ emb, const u16* __restrict__ projL,
        const u16* __restrict__ list, const int* __restrict__ count_ptr,
        int base, float* __restrict__ out) {
    constexpr int K8 = K / 8;
    constexpr int KS = K / 32;
    constexpr int LROW = K + 8;
    __shared__ __align__(16) u16 A[32][LROW];
    __shared__ u16 s_tok[32];
    __shared__ int s_loc[32];

    int count = *count_ptr;
    int t0 = blockIdx.x * 32;
    if (t0 >= count) return;
    int nt_valid = min(32, count - t0);
    int tid = threadIdx.x;

    if (tid < 32) {
        int tokidx = 0, loc = -1;
        if (tid < nt_valid) {
            tokidx = list[t0 + tid];
            loc = ids[tokidx] - base;
            if (loc == PAD) loc = -1;            // padding row -> zeros
        }
        s_tok[tid] = (u16)tokidx;
        s_loc[tid] = loc;
    }
    __syncthreads();

    for (int c = tid; c < 32 * K8; c += 256) {
        int m = c / K8, k8 = c % K8;
        int loc = s_loc[m];
        float4 v0 = make_float4(0.f,0.f,0.f,0.f), v1 = v0;
        if (loc >= 0) {
            const float4* p = (const float4*)(emb + (size_t)loc * K) + k8 * 2;
            v0 = p[0]; v1 = p[1];
        }
        u16 t[8] = {f2bf(v0.x), f2bf(v0.y), f2bf(v0.z), f2bf(v0.w),
                    f2bf(v1.x), f2bf(v1.y), f2bf(v1.z), f2bf(v1.w)};
        *(int4*)&A[m][k8 * 8] = *(const int4*)t;
    }
    __syncthreads();

    int wave = tid >> 6;
    int lane = tid & 63;
    int lr = lane & 15;
    int lk = (lane >> 4) * 8;
    const bf16x8* Bfrag = (const bf16x8*)projL;

    f32x4 acc[2][16] = {};
    for (int kstep = 0; kstep < KS; ++kstep) {
        bf16x8 a0 = *(const bf16x8*)&A[lr][kstep * 32 + lk];
        bf16x8 a1 = *(const bf16x8*)&A[16 + lr][kstep * 32 + lk];
        #pragma unroll
        for (int ntile = 0; ntile < 16; ++ntile) {
            bf16x8 b = Bfrag[((size_t)((wave * 16 + ntile) * KS + kstep)) * 64 + lane];
            acc[0][ntile] = __builtin_amdgcn_mfma_f32_16x16x32_bf16(a0, b, acc[0][ntile], 0, 0, 0);
            acc[1][ntile] = __builtin_amdgcn_mfma_f32_16x16x32_bf16(a1, b, acc[1][ntile], 0, 0, 0);
        }
    }

    // C/D layout (m89): col = lane&15, row = (lane>>4)*4 + reg
    int nb = wave * 256;
    int rbase = (lane >> 4) * 4;
    #pragma unroll
    for (int mt = 0; mt < 2; ++mt) {
        #pragma unroll
        for (int r = 0; r < 4; ++r) {
            int trow = mt * 16 + rbase + r;
            if (trow < nt_valid) {
                float* orow = out + (size_t)s_tok[trow] * DIM + nb + lr;
                #pragma unroll
                for (int ntile = 0; ntile < 16; ++ntile)
                    orow[ntile * 16] = acc[mt][ntile][r];
            }
        }
    }
}

extern "C" void kernel_launch(void* const* d_in, const int* in_sizes, int n_in,
                              void* d_out, int out_size, void* d_ws, size_t ws_size,
                              hipStream_t stream) {
    const int*   ids   = (const int*)d_in[0];
    const float* emb0  = (const float*)d_in[1];
    const float* emb1  = (const float*)d_in[2];
    const float* emb2  = (const float*)d_in[3];
    const float* proj1 = (const float*)d_in[4];
    const float* proj2 = (const float*)d_in[5];
    float* out = (float*)d_out;

    int* counters = (int*)d_ws;                          // [0]=count1, [16]=count2
    u16* list1  = (u16*)((char*)d_ws + 128);
    u16* list2  = list1 + NTOK;
    u16* projL1 = list2 + NTOK;                          // fragment-ordered bf16
    u16* projL2 = projL1 + NP1;

    hipMemsetAsync(d_ws, 0, 128, stream);                // reset counters every call
    classify_k<<<NTOK / 512, 512, 0, stream>>>(ids, list1, list2, counters);
    cvtprojL_k<K1><<<NP1 / (256 * 8), 256, 0, stream>>>(proj1, projL1);
    cvtprojL_k<K2><<<NP2 / (256 * 8), 256, 0, stream>>>(proj2, projL2);
    copy0_k<<<NTOK, 256, 0, stream>>>(ids, emb0, out);
    gemm_k<K1><<<NTOK / 32, 256, 0, stream>>>(ids, emb1, projL1, list1, &counters[0], C1, out);
    gemm_k<K2><<<NTOK / 32, 256, 0, stream>>>(ids, emb2, projL2, list2, &counters[16], C2, out);
}

// Round 4
// 66.386 us; speedup vs baseline: 6.3875x; 1.2758x over previous
//
#include <hip/hip_runtime.h>

// AdaptiveEmbedding: VOCAB=50000, cutoffs [20000,40000], EMBED_DIM=1024, pad=1
// cluster 0: ids [0,20000)     -> emb0 [20000,1024], direct f32 gather
// cluster 1: ids [20000,40000) -> emb1 [20000,256]  @ proj1[1024,256]^T  (bf16 MFMA)
// cluster 2: ids [40000,50000) -> emb2 [10000,64]   @ proj2[1024,64]^T   (bf16 MFMA)
//
// 2 launches: prep_k (classify + proj->bf16 fragment converts, fused by blockIdx)
//             fused_k (gemm1 | gemm2 | cluster0-copy fused by blockIdx, so the
//             HBM-bound copy overlaps the L2/MFMA-bound gemms)

constexpr int NTOK = 8 * 4096;
constexpr int C1 = 20000;
constexpr int C2 = 40000;
constexpr int DIM = 1024;
constexpr int PAD = 1;
constexpr int K1 = 256, K2 = 64;
constexpr int NP1 = DIM * K1;
constexpr int NP2 = DIM * K2;
constexpr int NB1 = NTOK / 64;   // 512 gemm1 blocks (64 tokens each, worst case)
constexpr int NB2 = NTOK / 64;   // 512 gemm2 blocks
constexpr int NBC = NTOK / 8;    // 4096 copy blocks (8 tokens each)

typedef unsigned short u16;
typedef unsigned int u32;
typedef unsigned long long u64;
typedef __attribute__((ext_vector_type(8))) short bf16x8;
typedef __attribute__((ext_vector_type(4))) float f32x4;

__device__ __forceinline__ u16 f2bf(float f) {   // RNE f32 -> bf16
    u32 u = __builtin_bit_cast(u32, f);
    return (u16)((u + 0x7FFFu + ((u >> 16) & 1u)) >> 16);
}

// proj (f32 [DIM][K]) -> bf16 MFMA fragment order: chunk idx = (ntile*KS+kstep)*64+lane
template<int K>
__device__ __forceinline__ void cvt_body(int idx, const float* __restrict__ src,
                                         u16* __restrict__ dst) {
    constexpr int KS = K / 32;
    int lane = idx & 63;
    int rest = idx >> 6;
    int kstep = rest % KS;
    int ntile = rest / KS;
    int n = ntile * 16 + (lane & 15);
    int k = kstep * 32 + (lane >> 4) * 8;
    const float4* p = (const float4*)(src + (size_t)n * K + k);
    float4 a = p[0], b = p[1];
    u16 t[8] = {f2bf(a.x), f2bf(a.y), f2bf(a.z), f2bf(a.w),
                f2bf(b.x), f2bf(b.y), f2bf(b.z), f2bf(b.w)};
    *(int4*)(dst + (size_t)idx * 8) = *(const int4*)t;
}

// blocks 0..63: compaction (one global atomic per list per block);
// blocks 64..127: cvt proj1; blocks 128..143: cvt proj2
__global__ __launch_bounds__(512) void prep_k(const int* __restrict__ ids,
        u16* __restrict__ list1, u16* __restrict__ list2, int* __restrict__ counters,
        const float* __restrict__ proj1, const float* __restrict__ proj2,
        u16* __restrict__ projL1, u16* __restrict__ projL2) {
    int b = blockIdx.x;
    int tid = threadIdx.x;
    if (b >= 64) {
        if (b < 128) cvt_body<K1>((b - 64) * 512 + tid, proj1, projL1);
        else         cvt_body<K2>((b - 128) * 512 + tid, proj2, projL2);
        return;
    }
    __shared__ int woff1[8], woff2[8];
    __shared__ int base1, base2;
    int i = b * 512 + tid;
    int id = ids[i];
    bool in1 = (id >= C1) & (id < C2);
    bool in2 = (id >= C2);
    u64 b1 = __ballot(in1);
    u64 b2 = __ballot(in2);
    int wave = tid >> 6, lane = tid & 63;
    if (lane == 0) { woff1[wave] = __popcll(b1); woff2[wave] = __popcll(b2); }
    __syncthreads();
    if (tid == 0) {
        int t1 = 0, t2 = 0;
        #pragma unroll
        for (int w = 0; w < 8; ++w) {
            int c1 = woff1[w]; woff1[w] = t1; t1 += c1;
            int c2 = woff2[w]; woff2[w] = t2; t2 += c2;
        }
        base1 = atomicAdd(&counters[0], t1);
        base2 = atomicAdd(&counters[16], t2);
    }
    __syncthreads();
    u64 lt = (lane == 63) ? ~0ull >> 1 : (1ull << lane) - 1;
    if (in1) list1[base1 + woff1[wave] + __popcll(b1 & lt)] = (u16)i;
    if (in2) list2[base2 + woff2[wave] + __popcll(b2 & lt)] = (u16)i;
}

// 64 tokens x 1024 outputs per block, 8 waves: wave = (mhalf 0/1) x (nquarter 0..3),
// each wave 2 m-tiles x 16 n-tiles, acc[2][16] f32x4. A in LDS bf16, row stride
// K+8 u16 (= 4 mod 32 words -> benign 2-way alias). B from fragment-ordered bf16
// (contiguous 1KB coalesced wave read, L2-resident).
template<int K>
__device__ __forceinline__ void gemm_body(int b, const int* __restrict__ ids,
        const float* __restrict__ emb, const u16* __restrict__ projL,
        const u16* __restrict__ list, const int* __restrict__ count_ptr,
        int base, float* __restrict__ out,
        u16* __restrict__ A, u16* __restrict__ s_tok, int* __restrict__ s_loc) {
    constexpr int K8 = K / 8;
    constexpr int KS = K / 32;
    constexpr int LROW = K + 8;
    int count = *count_ptr;
    int t0 = b * 64;
    if (t0 >= count) return;
    int nt_valid = min(64, count - t0);
    int tid = threadIdx.x;

    if (tid < 64) {
        int tokidx = 0, loc = -1;
        if (tid < nt_valid) {
            tokidx = list[t0 + tid];
            loc = ids[tokidx] - base;
            if (loc == PAD) loc = -1;            // padding row -> zeros
        }
        s_tok[tid] = (u16)tokidx;
        s_loc[tid] = loc;
    }
    __syncthreads();

    for (int c = tid; c < 64 * K8; c += 512) {
        int m = c / K8, k8 = c % K8;
        int loc = s_loc[m];
        float4 v0 = make_float4(0.f,0.f,0.f,0.f), v1 = v0;
        if (loc >= 0) {
            const float4* p = (const float4*)(emb + (size_t)loc * K) + k8 * 2;
            v0 = p[0]; v1 = p[1];
        }
        u16 t[8] = {f2bf(v0.x), f2bf(v0.y), f2bf(v0.z), f2bf(v0.w),
                    f2bf(v1.x), f2bf(v1.y), f2bf(v1.z), f2bf(v1.w)};
        *(int4*)&A[m * LROW + k8 * 8] = *(const int4*)t;
    }
    __syncthreads();

    int wave = tid >> 6;
    int lane = tid & 63;
    int mh = (wave >> 2) * 32;     // m half: rows [mh, mh+32)
    int nq = wave & 3;             // n quarter: cols [nq*256, +256)
    int lr = lane & 15;
    int lk = (lane >> 4) * 8;
    const bf16x8* Bfrag = (const bf16x8*)projL;

    f32x4 acc[2][16] = {};
    for (int ks = 0; ks < KS; ++ks) {
        bf16x8 a0 = *(const bf16x8*)&A[(mh + lr) * LROW + ks * 32 + lk];
        bf16x8 a1 = *(const bf16x8*)&A[(mh + 16 + lr) * LROW + ks * 32 + lk];
        #pragma unroll
        for (int nt = 0; nt < 16; ++nt) {
            bf16x8 bb = Bfrag[((size_t)((nq * 16 + nt) * KS + ks)) * 64 + lane];
            acc[0][nt] = __builtin_amdgcn_mfma_f32_16x16x32_bf16(a0, bb, acc[0][nt], 0, 0, 0);
            acc[1][nt] = __builtin_amdgcn_mfma_f32_16x16x32_bf16(a1, bb, acc[1][nt], 0, 0, 0);
        }
    }

    // C/D layout (m89): col = lane&15, row = (lane>>4)*4 + reg
    int nb = nq * 256;
    int rbase = (lane >> 4) * 4;
    #pragma unroll
    for (int mt = 0; mt < 2; ++mt) {
        #pragma unroll
        for (int r = 0; r < 4; ++r) {
            int trow = mh + mt * 16 + rbase + r;
            if (trow < nt_valid) {
                float* orow = out + (size_t)s_tok[trow] * DIM + nb + lr;
                #pragma unroll
                for (int nt = 0; nt < 16; ++nt)
                    orow[nt * 16] = acc[mt][nt][r];
            }
        }
    }
}

__global__ __launch_bounds__(512) void fused_k(const int* __restrict__ ids,
        const float* __restrict__ emb0, const float* __restrict__ emb1,
        const float* __restrict__ emb2, const u16* __restrict__ projL1,
        const u16* __restrict__ projL2, const u16* __restrict__ list1,
        const u16* __restrict__ list2, const int* __restrict__ counters,
        float* __restrict__ out) {
    __shared__ __align__(16) u16 A[64 * (K1 + 8)];
    __shared__ u16 s_tok[64];
    __shared__ int s_loc[64];
    int b = blockIdx.x;
    if (b < NB1) {
        gemm_body<K1>(b, ids, emb1, projL1, list1, &counters[0], C1, out, A, s_tok, s_loc);
        return;
    }
    b -= NB1;
    if (b < NB2) {
        gemm_body<K2>(b, ids, emb2, projL2, list2, &counters[16], C2, out, A, s_tok, s_loc);
        return;
    }
    b -= NB2;
    // cluster 0 copy: 8 tokens per block, 512 threads x 4 float4 each
    int base = b * 8;
    int tid = threadIdx.x;
    const float4* e4 = (const float4*)emb0;
    float4* o4 = (float4*)out;
    #pragma unroll
    for (int r = 0; r < 4; ++r) {
        int j = r * 512 + tid;          // float4 index within the 8 rows
        int tok = base + (j >> 8);      // 256 float4 per row
        int d4 = j & 255;
        int id = ids[tok];
        if (id < C1) {
            float4 v = make_float4(0.f, 0.f, 0.f, 0.f);
            if (id != PAD) v = e4[(size_t)id * 256 + d4];
            o4[(size_t)tok * 256 + d4] = v;
        }
    }
}

extern "C" void kernel_launch(void* const* d_in, const int* in_sizes, int n_in,
                              void* d_out, int out_size, void* d_ws, size_t ws_size,
                              hipStream_t stream) {
    const int*   ids   = (const int*)d_in[0];
    const float* emb0  = (const float*)d_in[1];
    const float* emb1  = (const float*)d_in[2];
    const float* emb2  = (const float*)d_in[3];
    const float* proj1 = (const float*)d_in[4];
    const float* proj2 = (const float*)d_in[5];
    float* out = (float*)d_out;

    int* counters = (int*)d_ws;                          // [0]=count1, [16]=count2
    u16* list1  = (u16*)((char*)d_ws + 128);
    u16* list2  = list1 + NTOK;
    u16* projL1 = list2 + NTOK;                          // fragment-ordered bf16
    u16* projL2 = projL1 + NP1;

    hipMemsetAsync(d_ws, 0, 128, stream);                // reset counters every call
    prep_k<<<144, 512, 0, stream>>>(ids, list1, list2, counters,
                                    proj1, proj2, projL1, projL2);
    fused_k<<<NB1 + NB2 + NBC, 512, 0, stream>>>(ids, emb0, emb1, emb2,
                                                 projL1, projL2, list1, list2,
                                                 counters, out);
}

// Round 6
// 64.289 us; speedup vs baseline: 6.5959x; 1.0326x over previous
//
#include <hip/hip_runtime.h>

// AdaptiveEmbedding: VOCAB=50000, cutoffs [20000,40000], EMBED_DIM=1024, pad=1
// cluster 0: ids [0,20000)     -> emb0 [20000,1024], direct f32 gather
// cluster 1: ids [20000,40000) -> emb1 [20000,256]  @ proj1[1024,256]^T  (bf16 MFMA)
// cluster 2: ids [40000,50000) -> emb2 [10000,64]   @ proj2[1024,64]^T   (bf16 MFMA)
//
// prep_k: classify + proj->bf16 fragment converts.
// fused_k: roles interleaved per-blockIdx (1 gemm1 : 1 gemm2 : 4 copy per stripe
// of 6) so HBM-bound copy overlaps L2/MFMA-bound gemm all kernel long.
// Regs <=128/wave (acc[2][8] = 64 AGPR) -> 4 waves/SIMD -> 2 blocks/CU.

constexpr int NTOK = 8 * 4096;
constexpr int C1 = 20000;
constexpr int C2 = 40000;
constexpr int DIM = 1024;
constexpr int PAD = 1;
constexpr int K1 = 256, K2 = 64;
constexpr int NP1 = DIM * K1;
constexpr int NP2 = DIM * K2;
constexpr int GTOK = 32;             // tokens per gemm block
constexpr int NB1 = NTOK / GTOK;     // 1024
constexpr int NB2 = NTOK / GTOK;     // 1024

typedef unsigned short u16;
typedef unsigned int u32;
typedef unsigned long long u64;
typedef __attribute__((ext_vector_type(8))) short bf16x8;
typedef __attribute__((ext_vector_type(4))) float f32x4;

__device__ __forceinline__ u16 f2bf(float f) {   // RNE f32 -> bf16
    u32 u = __builtin_bit_cast(u32, f);
    return (u16)((u + 0x7FFFu + ((u >> 16) & 1u)) >> 16);
}

__device__ __forceinline__ void nt_store4(const float4& v, float4* p) {
    f32x4 w = {v.x, v.y, v.z, v.w};
    __builtin_nontemporal_store(w, (f32x4*)p);
}

// proj (f32 [DIM][K]) -> bf16 MFMA fragment order: chunk idx = (ntile*KS+kstep)*64+lane
template<int K>
__device__ __forceinline__ void cvt_body(int idx, const float* __restrict__ src,
                                         u16* __restrict__ dst) {
    constexpr int KS = K / 32;
    int lane = idx & 63;
    int rest = idx >> 6;
    int kstep = rest % KS;
    int ntile = rest / KS;
    int n = ntile * 16 + (lane & 15);
    int k = kstep * 32 + (lane >> 4) * 8;
    const float4* p = (const float4*)(src + (size_t)n * K + k);
    float4 a = p[0], b = p[1];
    u16 t[8] = {f2bf(a.x), f2bf(a.y), f2bf(a.z), f2bf(a.w),
                f2bf(b.x), f2bf(b.y), f2bf(b.z), f2bf(b.w)};
    *(int4*)(dst + (size_t)idx * 8) = *(const int4*)t;
}

// blocks 0..63: compaction (one global atomic per list per block);
// blocks 64..127: cvt proj1; blocks 128..143: cvt proj2
__global__ __launch_bounds__(512) void prep_k(const int* __restrict__ ids,
        u16* __restrict__ list1, u16* __restrict__ list2, int* __restrict__ counters,
        const float* __restrict__ proj1, const float* __restrict__ proj2,
        u16* __restrict__ projL1, u16* __restrict__ projL2) {
    int b = blockIdx.x;
    int tid = threadIdx.x;
    if (b >= 64) {
        if (b < 128) cvt_body<K1>((b - 64) * 512 + tid, proj1, projL1);
        else         cvt_body<K2>((b - 128) * 512 + tid, proj2, projL2);
        return;
    }
    __shared__ int woff1[8], woff2[8];
    __shared__ int base1, base2;
    int i = b * 512 + tid;
    int id = ids[i];
    bool in1 = (id >= C1) & (id < C2);
    bool in2 = (id >= C2);
    u64 b1 = __ballot(in1);
    u64 b2 = __ballot(in2);
    int wave = tid >> 6, lane = tid & 63;
    if (lane == 0) { woff1[wave] = __popcll(b1); woff2[wave] = __popcll(b2); }
    __syncthreads();
    if (tid == 0) {
        int t1 = 0, t2 = 0;
        #pragma unroll
        for (int w = 0; w < 8; ++w) {
            int c1 = woff1[w]; woff1[w] = t1; t1 += c1;
            int c2 = woff2[w]; woff2[w] = t2; t2 += c2;
        }
        base1 = atomicAdd(&counters[0], t1);
        base2 = atomicAdd(&counters[16], t2);
    }
    __syncthreads();
    u64 lt = (lane == 63) ? ~0ull >> 1 : (1ull << lane) - 1;
    if (in1) list1[base1 + woff1[wave] + __popcll(b1 & lt)] = (u16)i;
    if (in2) list2[base2 + woff2[wave] + __popcll(b2 & lt)] = (u16)i;
}

// gemm: 32 tokens x 1024 outputs per block. 8 waves; wave w owns n-tiles
// [w*8, w*8+8) x both m-tiles -> acc[2][8] f32x4 = 64 AGPR. A staged in LDS
// bf16 (row stride K+8 u16 -> benign 2-way alias); B from fragment-ordered
// bf16 (each fragment one contiguous 1KB coalesced wave read, L2-resident,
// reused by 2 MFMAs).
template<int K>
__device__ __forceinline__ void gemm_body(int b, const int* __restrict__ ids,
        const float* __restrict__ emb, const u16* __restrict__ projL,
        const u16* __restrict__ list, const int* __restrict__ count_ptr,
        int base, float* __restrict__ out,
        u16* __restrict__ A, u16* __restrict__ s_tok, int* __restrict__ s_loc) {
    constexpr int K8 = K / 8;
    constexpr int KS = K / 32;
    constexpr int LROW = K + 8;
    int count = *count_ptr;
    int t0 = b * GTOK;
    if (t0 >= count) return;
    int nt_valid = min(GTOK, count - t0);
    int tid = threadIdx.x;

    if (tid < GTOK) {
        int tokidx = 0, loc = -1;
        if (tid < nt_valid) {
            tokidx = list[t0 + tid];
            loc = ids[tokidx] - base;
            if (loc == PAD) loc = -1;            // padding row -> zeros
        }
        s_tok[tid] = (u16)tokidx;
        s_loc[tid] = loc;
    }
    __syncthreads();

    for (int c = tid; c < GTOK * K8; c += 512) {
        int m = c / K8, k8 = c % K8;
        int loc = s_loc[m];
        float4 v0 = make_float4(0.f,0.f,0.f,0.f), v1 = v0;
        if (loc >= 0) {
            const float4* p = (const float4*)(emb + (size_t)loc * K) + k8 * 2;
            v0 = p[0]; v1 = p[1];
        }
        u16 t[8] = {f2bf(v0.x), f2bf(v0.y), f2bf(v0.z), f2bf(v0.w),
                    f2bf(v1.x), f2bf(v1.y), f2bf(v1.z), f2bf(v1.w)};
        *(int4*)&A[m * LROW + k8 * 8] = *(const int4*)t;
    }
    __syncthreads();

    int wave = tid >> 6;
    int lane = tid & 63;
    int lr = lane & 15;
    int lk = (lane >> 4) * 8;
    const bf16x8* Bfrag = (const bf16x8*)projL;

    f32x4 acc[2][8] = {};
    for (int ks = 0; ks < KS; ++ks) {
        bf16x8 a0 = *(const bf16x8*)&A[lr * LROW + ks * 32 + lk];
        bf16x8 a1 = *(const bf16x8*)&A[(16 + lr) * LROW + ks * 32 + lk];
        #pragma unroll
        for (int nt = 0; nt < 8; ++nt) {
            bf16x8 bb = Bfrag[((size_t)((wave * 8 + nt) * KS + ks)) * 64 + lane];
            acc[0][nt] = __builtin_amdgcn_mfma_f32_16x16x32_bf16(a0, bb, acc[0][nt], 0, 0, 0);
            acc[1][nt] = __builtin_amdgcn_mfma_f32_16x16x32_bf16(a1, bb, acc[1][nt], 0, 0, 0);
        }
    }

    // C/D layout (m89): col = lane&15, row = (lane>>4)*4 + reg
    int nb = wave * 128;
    int rbase = (lane >> 4) * 4;
    #pragma unroll
    for (int mt = 0; mt < 2; ++mt) {
        #pragma unroll
        for (int r = 0; r < 4; ++r) {
            int trow = mt * 16 + rbase + r;
            if (trow < nt_valid) {
                float* orow = out + (size_t)s_tok[trow] * DIM + nb + lr;
                #pragma unroll
                for (int nt = 0; nt < 8; ++nt)
                    __builtin_nontemporal_store(acc[mt][nt][r], &orow[nt * 16]);
            }
        }
    }
}

__global__ __launch_bounds__(512, 4) void fused_k(const int* __restrict__ ids,
        const float* __restrict__ emb0, const float* __restrict__ emb1,
        const float* __restrict__ emb2, const u16* __restrict__ projL1,
        const u16* __restrict__ projL2, const u16* __restrict__ list1,
        const u16* __restrict__ list2, const int* __restrict__ counters,
        float* __restrict__ out) {
    __shared__ __align__(16) u16 A[GTOK * (K1 + 8)];
    __shared__ u16 s_tok[GTOK];
    __shared__ int s_loc[GTOK];
    // stripe of 6: [gemm1, gemm2, copy, copy, copy, copy]
    int b = blockIdx.x;
    int stripe = b / 6;
    int role = b % 6;
    if (role == 0) {
        gemm_body<K1>(stripe, ids, emb1, projL1, list1, &counters[0], C1, out, A, s_tok, s_loc);
        return;
    }
    if (role == 1) {
        gemm_body<K2>(stripe, ids, emb2, projL2, list2, &counters[16], C2, out, A, s_tok, s_loc);
        return;
    }
    // cluster 0 copy: 8 tokens per block, 512 threads x 4 float4 each
    int cb = stripe * 4 + (role - 2);
    int tbase = cb * 8;
    int tid = threadIdx.x;
    const float4* e4 = (const float4*)emb0;
    float4* o4 = (float4*)out;
    #pragma unroll
    for (int r = 0; r < 4; ++r) {
        int j = r * 512 + tid;          // float4 index within the 8 rows
        int tok = tbase + (j >> 8);     // 256 float4 per row
        int d4 = j & 255;
        int id = ids[tok];
        if (id < C1) {
            float4 v = make_float4(0.f, 0.f, 0.f, 0.f);
            if (id != PAD) v = e4[(size_t)id * 256 + d4];
            nt_store4(v, &o4[(size_t)tok * 256 + d4]);
        }
    }
}

extern "C" void kernel_launch(void* const* d_in, const int* in_sizes, int n_in,
                              void* d_out, int out_size, void* d_ws, size_t ws_size,
                              hipStream_t stream) {
    const int*   ids   = (const int*)d_in[0];
    const float* emb0  = (const float*)d_in[1];
    const float* emb1  = (const float*)d_in[2];
    const float* emb2  = (const float*)d_in[3];
    const float* proj1 = (const float*)d_in[4];
    const float* proj2 = (const float*)d_in[5];
    float* out = (float*)d_out;

    int* counters = (int*)d_ws;                          // [0]=count1, [16]=count2
    u16* list1  = (u16*)((char*)d_ws + 128);
    u16* list2  = list1 + NTOK;
    u16* projL1 = list2 + NTOK;                          // fragment-ordered bf16
    u16* projL2 = projL1 + NP1;

    hipMemsetAsync(d_ws, 0, 128, stream);                // reset counters every call
    prep_k<<<144, 512, 0, stream>>>(ids, list1, list2, counters,
                                    proj1, proj2, projL1, projL2);
    fused_k<<<NB1 * 6, 512, 0, stream>>>(ids, emb0, emb1, emb2,
                                         projL1, projL2, list1, list2,
                                         counters, out);
}